// Round 4
// baseline (256.492 us; speedup 1.0000x reference)
//
#include <hip/hip_runtime.h>

// y[e, o] = sum_i weight[widx[e]][o][i] * values[iidx[e]][i]
// E = 1e6, N_W = 1024, D_IN = D_OUT = 16, fp32.
//
// R1: weight gather latency-bound -> 137 us.
// R2: global-atomic scatter serialized -> 203 us scatter.
// R3: deterministic sort OK, but bucket_mv random-transaction-bound: 4
//     redundant 16B sector loads per connection on the x-gather (separate
//     instrs never line-merge), perm->x serial chain, ~2 iters/thread ->
//     89 us with HBM nearly idle on warm replays.
// R4: move the x-gather into the scatter kernel (4 lanes/conn, lane j loads
//     quarter j -> one merged full-line request per connection, max MLP,
//     no dependent chain). bucket_mv then STREAMS xs contiguously (L1
//     absorbs redundancy), W in 64 VGPRs, scattered out-store is
//     fire-and-forget full 64B lines.

#define D 16
#define NWMAX 1024
#define NB 256      // sort blocks == chunks
#define BT 256      // threads per block
#define SEG 8

// ---------------- fallback naive kernel (R1, 137us) ----------------
__global__ __launch_bounds__(256) void linear_gather_mv(
    const float* __restrict__ values, const float* __restrict__ weight,
    const int* __restrict__ input_idx, const int* __restrict__ weight_idx,
    float* __restrict__ out, int E)
{
    int tid = blockIdx.x * blockDim.x + threadIdx.x;
    int e = tid >> 2;
    int j = tid & 3;
    if (e >= E) return;
    int ii = input_idx[e];
    int wi = weight_idx[e];
    const float4* xp = (const float4*)(values + (long long)ii * D);
    float4 x0 = xp[0], x1 = xp[1], x2 = xp[2], x3 = xp[3];
    const float4* wp = (const float4*)(weight + (long long)wi * (D * D) + j * (4 * D));
    float4 acc;
    float* accp = (float*)&acc;
    #pragma unroll
    for (int r = 0; r < 4; ++r) {
        float4 w0 = wp[r * 4 + 0], w1 = wp[r * 4 + 1], w2 = wp[r * 4 + 2], w3 = wp[r * 4 + 3];
        accp[r] = w0.x * x0.x + w0.y * x0.y + w0.z * x0.z + w0.w * x0.w
                + w1.x * x1.x + w1.y * x1.y + w1.z * x1.z + w1.w * x1.w
                + w2.x * x2.x + w2.y * x2.y + w2.z * x2.z + w2.w * x2.w
                + w3.x * x3.x + w3.y * x3.y + w3.z * x3.z + w3.w * x3.w;
    }
    ((float4*)out)[(long long)e * 4 + j] = acc;
}

// ---------------- phase 1: per-block private histograms ----------------
__global__ __launch_bounds__(BT) void hist_blocks(
    const int* __restrict__ widx, int E, int chunk,
    int* __restrict__ hist2d, int NW)
{
    __shared__ int lh[NWMAX];
    for (int i = threadIdx.x; i < NW; i += BT) lh[i] = 0;
    __syncthreads();
    int s0 = blockIdx.x * chunk;
    int s1 = min(E, s0 + chunk);
    for (int e = s0 + threadIdx.x; e < s1; e += BT)
        atomicAdd(&lh[widx[e]], 1);   // LDS atomic only
    __syncthreads();
    int* row = hist2d + (long long)blockIdx.x * NW;
    for (int i = threadIdx.x; i < NW; i += BT) row[i] = lh[i];
}

// ------- phase 2a: per-bin exclusive scan across blocks (in place) -------
__global__ __launch_bounds__(NB) void scan_per_bin(
    int* __restrict__ hist2d, int* __restrict__ total, int NW)
{
    __shared__ int buf[2 * NB];
    int b = blockIdx.x;   // bin
    int t = threadIdx.x;  // sort-block index
    int v = hist2d[(long long)t * NW + b];
    buf[t] = v;
    __syncthreads();
    int pin = 0;
    for (int off = 1; off < NB; off <<= 1) {
        int x = buf[pin * NB + t];
        if (t >= off) x += buf[pin * NB + t - off];
        buf[(1 - pin) * NB + t] = x;
        pin = 1 - pin;
        __syncthreads();
    }
    int incl = buf[pin * NB + t];
    hist2d[(long long)t * NW + b] = incl - v;   // exclusive prefix for (bin, block)
    if (t == NB - 1) total[b] = incl;
}

// ---------------- phase 2b: scan over bins -> bucket offsets ----------------
__global__ __launch_bounds__(1024) void scan_bins(
    const int* __restrict__ total, int* __restrict__ offsets, int NW)
{
    __shared__ int buf[2 * NWMAX];
    int t = threadIdx.x;
    int v = (t < NW) ? total[t] : 0;
    buf[t] = v;
    __syncthreads();
    int pin = 0;
    for (int off = 1; off < NWMAX; off <<= 1) {
        int x = buf[pin * NWMAX + t];
        if (t >= off) x += buf[pin * NWMAX + t - off];
        buf[(1 - pin) * NWMAX + t] = x;
        pin = 1 - pin;
        __syncthreads();
    }
    int incl = buf[pin * NWMAX + t];
    if (t < NW) {
        offsets[t + 1] = incl;
        if (t == 0) offsets[0] = 0;
    }
}

// ------- phase 3 (R4): scatter + x-gather fused, full-line merged -------
// 4 lanes per connection; lane j loads/stores quarter j of the 64B x-row.
__global__ __launch_bounds__(BT) void gather_scatter(
    const int* __restrict__ widx, const int* __restrict__ iidx,
    const float* __restrict__ values, int E, int chunk,
    const int* __restrict__ hist2d, const int* __restrict__ offsets,
    float* __restrict__ xs, int* __restrict__ pe, int NW)
{
    __shared__ int cur[NWMAX];
    int p = blockIdx.x;
    const int* row = hist2d + (long long)p * NW;
    for (int i = threadIdx.x; i < NW; i += BT)
        cur[i] = offsets[i] + row[i];
    __syncthreads();
    int t = threadIdx.x;
    int j = t & 3;
    int s0 = p * chunk;
    int s1 = min(E, s0 + chunk);
    for (int e = s0 + (t >> 2); e < s1; e += BT / 4) {
        int wi = widx[e];           // 4 lanes same addr -> broadcast
        int ii = iidx[e];
        int pos = 0;
        if (j == 0) pos = atomicAdd(&cur[wi], 1);   // LDS atomic, 1 per conn
        pos = __shfl(pos, t & ~3);                  // broadcast within group
        float4 xq = ((const float4*)(values + (long long)ii * D))[j];
        ((float4*)(xs + (long long)pos * D))[j] = xq;
        if (j == 0) pe[pos] = e;
    }
}

// ------- phase 4 (R4): streaming per-bucket matvec, W in registers -------
__global__ __launch_bounds__(256) void bucket_mv_stream(
    const float* __restrict__ xs, const float* __restrict__ weight,
    const int* __restrict__ offsets, const int* __restrict__ pe,
    float* __restrict__ out)
{
    int b = blockIdx.x;
    int lo = offsets[b], hi = offsets[b + 1];
    int cnt = hi - lo;
    if (cnt == 0) return;
    int per = (cnt + SEG - 1) / SEG;
    int s0 = lo + blockIdx.y * per;
    int s1 = min(hi, s0 + per);
    if (s0 >= s1) return;

    int j = threadIdx.x & 3;
    int g = threadIdx.x >> 2;

    const float4* wp = (const float4*)(weight + (long long)b * (D * D) + j * (4 * D));
    float4 w00 = wp[0],  w01 = wp[1],  w02 = wp[2],  w03 = wp[3];
    float4 w10 = wp[4],  w11 = wp[5],  w12 = wp[6],  w13 = wp[7];
    float4 w20 = wp[8],  w21 = wp[9],  w22 = wp[10], w23 = wp[11];
    float4 w30 = wp[12], w31 = wp[13], w32 = wp[14], w33 = wp[15];

    for (int k = s0 + g; k < s1; k += 64) {
        int e = pe[k];
        const float4* xp = (const float4*)(xs + (long long)k * D);  // contiguous!
        float4 x0 = xp[0], x1 = xp[1], x2 = xp[2], x3 = xp[3];

        float4 acc;
        acc.x = w00.x * x0.x + w00.y * x0.y + w00.z * x0.z + w00.w * x0.w
              + w01.x * x1.x + w01.y * x1.y + w01.z * x1.z + w01.w * x1.w
              + w02.x * x2.x + w02.y * x2.y + w02.z * x2.z + w02.w * x2.w
              + w03.x * x3.x + w03.y * x3.y + w03.z * x3.z + w03.w * x3.w;
        acc.y = w10.x * x0.x + w10.y * x0.y + w10.z * x0.z + w10.w * x0.w
              + w11.x * x1.x + w11.y * x1.y + w11.z * x1.z + w11.w * x1.w
              + w12.x * x2.x + w12.y * x2.y + w12.z * x2.z + w12.w * x2.w
              + w13.x * x3.x + w13.y * x3.y + w13.z * x3.z + w13.w * x3.w;
        acc.z = w20.x * x0.x + w20.y * x0.y + w20.z * x0.z + w20.w * x0.w
              + w21.x * x1.x + w21.y * x1.y + w21.z * x1.z + w21.w * x1.w
              + w22.x * x2.x + w22.y * x2.y + w22.z * x2.z + w22.w * x2.w
              + w23.x * x3.x + w23.y * x3.y + w23.z * x3.z + w23.w * x3.w;
        acc.w = w30.x * x0.x + w30.y * x0.y + w30.z * x0.z + w30.w * x0.w
              + w31.x * x1.x + w31.y * x1.y + w31.z * x1.z + w31.w * x1.w
              + w32.x * x2.x + w32.y * x2.y + w32.z * x2.z + w32.w * x2.w
              + w33.x * x3.x + w33.y * x3.y + w33.z * x3.z + w33.w * x3.w;

        ((float4*)out)[(long long)e * 4 + j] = acc;   // scattered, fire-and-forget
    }
}

// ------- R3 fallback scatter (int2 perm) + bucket_mv, kept as tier 2 -------
__global__ __launch_bounds__(BT) void scatter_det(
    const int* __restrict__ widx, const int* __restrict__ iidx, int E, int chunk,
    const int* __restrict__ hist2d, const int* __restrict__ offsets,
    int2* __restrict__ perm, int NW)
{
    __shared__ int cur[NWMAX];
    int p = blockIdx.x;
    const int* row = hist2d + (long long)p * NW;
    for (int i = threadIdx.x; i < NW; i += BT)
        cur[i] = offsets[i] + row[i];
    __syncthreads();
    int s0 = p * chunk;
    int s1 = min(E, s0 + chunk);
    for (int e = s0 + threadIdx.x; e < s1; e += BT) {
        int wi = widx[e];
        int pos = atomicAdd(&cur[wi], 1);
        perm[pos] = make_int2(e, iidx[e]);
    }
}

__global__ __launch_bounds__(256) void bucket_mv(
    const float* __restrict__ values, const float* __restrict__ weight,
    const int* __restrict__ offsets, const int2* __restrict__ perm,
    float* __restrict__ out)
{
    int b = blockIdx.x;
    int lo = offsets[b], hi = offsets[b + 1];
    int cnt = hi - lo;
    if (cnt == 0) return;
    int per = (cnt + SEG - 1) / SEG;
    int s0 = lo + blockIdx.y * per;
    int s1 = min(hi, s0 + per);
    if (s0 >= s1) return;
    int j = threadIdx.x & 3;
    int g = threadIdx.x >> 2;
    const float4* wp = (const float4*)(weight + (long long)b * (D * D) + j * (4 * D));
    float4 w00 = wp[0],  w01 = wp[1],  w02 = wp[2],  w03 = wp[3];
    float4 w10 = wp[4],  w11 = wp[5],  w12 = wp[6],  w13 = wp[7];
    float4 w20 = wp[8],  w21 = wp[9],  w22 = wp[10], w23 = wp[11];
    float4 w30 = wp[12], w31 = wp[13], w32 = wp[14], w33 = wp[15];
    for (int k = s0 + g; k < s1; k += 64) {
        int2 pe2 = perm[k];
        const float4* xp = (const float4*)(values + (long long)pe2.y * D);
        float4 x0 = xp[0], x1 = xp[1], x2 = xp[2], x3 = xp[3];
        float4 acc;
        acc.x = w00.x * x0.x + w00.y * x0.y + w00.z * x0.z + w00.w * x0.w
              + w01.x * x1.x + w01.y * x1.y + w01.z * x1.z + w01.w * x1.w
              + w02.x * x2.x + w02.y * x2.y + w02.z * x2.z + w02.w * x2.w
              + w03.x * x3.x + w03.y * x3.y + w03.z * x3.z + w03.w * x3.w;
        acc.y = w10.x * x0.x + w10.y * x0.y + w10.z * x0.z + w10.w * x0.w
              + w11.x * x1.x + w11.y * x1.y + w11.z * x1.z + w11.w * x1.w
              + w12.x * x2.x + w12.y * x2.y + w12.z * x2.z + w12.w * x2.w
              + w13.x * x3.x + w13.y * x3.y + w13.z * x3.z + w13.w * x3.w;
        acc.z = w20.x * x0.x + w20.y * x0.y + w20.z * x0.z + w20.w * x0.w
              + w21.x * x1.x + w21.y * x1.y + w21.z * x1.z + w21.w * x1.w
              + w22.x * x2.x + w22.y * x2.y + w22.z * x2.z + w22.w * x2.w
              + w23.x * x3.x + w23.y * x3.y + w23.z * x3.z + w23.w * x3.w;
        acc.w = w30.x * x0.x + w30.y * x0.y + w30.z * x0.z + w30.w * x0.w
              + w31.x * x1.x + w31.y * x1.y + w31.z * x1.z + w31.w * x1.w
              + w32.x * x2.x + w32.y * x2.y + w32.z * x2.z + w32.w * x2.w
              + w33.x * x3.x + w33.y * x3.y + w33.z * x3.z + w33.w * x3.w;
        ((float4*)out)[(long long)pe2.x * 4 + j] = acc;
    }
}

extern "C" void kernel_launch(void* const* d_in, const int* in_sizes, int n_in,
                              void* d_out, int out_size, void* d_ws, size_t ws_size,
                              hipStream_t stream) {
    const float* values     = (const float*)d_in[0];
    const float* weight     = (const float*)d_in[1];
    const int*   input_idx  = (const int*)d_in[2];
    const int*   weight_idx = (const int*)d_in[3];
    float*       out        = (float*)d_out;

    int E  = in_sizes[2];
    int NW = in_sizes[1] / (D * D);
    int chunk = (E + NB - 1) / NB;

    // Tier 1 (R4): xs[E*16] | hist2d[NB*NW] | total[NW] | offsets[NW+1] | pe[E]
    size_t n_xs   = (size_t)E * D;
    size_t n_hist = (size_t)NB * NW;
    size_t need1  = (n_xs + n_hist + NW + NW + 1 + (size_t)E) * sizeof(int);

    if (NW <= NWMAX && ws_size >= need1) {
        float* xs    = (float*)d_ws;
        int* hist2d  = (int*)d_ws + n_xs;
        int* total   = hist2d + n_hist;
        int* offsets = total + NW;
        int* pe      = offsets + NW + 1;

        hipLaunchKernelGGL(hist_blocks, dim3(NB), dim3(BT), 0, stream,
                           weight_idx, E, chunk, hist2d, NW);
        hipLaunchKernelGGL(scan_per_bin, dim3(NW), dim3(NB), 0, stream,
                           hist2d, total, NW);
        hipLaunchKernelGGL(scan_bins, dim3(1), dim3(1024), 0, stream,
                           total, offsets, NW);
        hipLaunchKernelGGL(gather_scatter, dim3(NB), dim3(BT), 0, stream,
                           weight_idx, input_idx, values, E, chunk,
                           hist2d, offsets, xs, pe, NW);
        hipLaunchKernelGGL(bucket_mv_stream, dim3(NW, SEG), dim3(256), 0, stream,
                           xs, weight, offsets, pe, out);
        return;
    }

    // Tier 2 (R3): hist2d | total | offsets | pad | perm[2E]
    size_t n_head = n_hist + NW + NW + 1;
    n_head = (n_head + 1) & ~(size_t)1;
    size_t need2 = (n_head + 2 * (size_t)E) * sizeof(int);

    if (NW <= NWMAX && ws_size >= need2) {
        int* hist2d  = (int*)d_ws;
        int* total   = hist2d + n_hist;
        int* offsets = total + NW;
        int2* perm   = (int2*)((int*)d_ws + n_head);

        hipLaunchKernelGGL(hist_blocks, dim3(NB), dim3(BT), 0, stream,
                           weight_idx, E, chunk, hist2d, NW);
        hipLaunchKernelGGL(scan_per_bin, dim3(NW), dim3(NB), 0, stream,
                           hist2d, total, NW);
        hipLaunchKernelGGL(scan_bins, dim3(1), dim3(1024), 0, stream,
                           total, offsets, NW);
        hipLaunchKernelGGL(scatter_det, dim3(NB), dim3(BT), 0, stream,
                           weight_idx, input_idx, E, chunk, hist2d, offsets, perm, NW);
        hipLaunchKernelGGL(bucket_mv, dim3(NW, SEG), dim3(256), 0, stream,
                           values, weight, offsets, perm, out);
        return;
    }

    // Tier 3: naive
    int total_thr = E * 4;
    int grid = (total_thr + 255) / 256;
    hipLaunchKernelGGL(linear_gather_mv, dim3(grid), dim3(256), 0, stream,
                       values, weight, input_idx, weight_idx, out, E);
}

// Round 5
// 166.280 us; speedup vs baseline: 1.5425x; 1.5425x over previous
//
#include <hip/hip_runtime.h>

// y[e, o] = sum_i weight[widx[e]][o][i] * values[iidx[e]][i]
// E = 1e6, N_W = 1024, D_IN = D_OUT = 16, fp32.
//
// R1: weight gather TA/latency-bound -> 137 us.
// R2: global-atomic scatter serialized -> 203 us.
// R3: sort OK, but bucket_mv VGPR_Count=44 -> compiler NEVER kept the 64-reg
//     W resident; it re-fetched W from L2 every iteration -> 89 us.
// R4: xs round-trip added 128MB + gather at 10% occupancy -> worse.
// R5: back to R3 structure, with:
//     - bucket_mv __launch_bounds__(256,4): explicit 128-VGPR budget so
//       W (64 VGPRs) stays resident; verify via VGPR_Count ~110+.
//     - 2-way unroll: two independent perm->x chains in flight per group.
//     - SEG=4 (grid NW x 4), ~4 iterations per group.
//     - sort-phase blocks at 1024 threads (16 waves/CU, was 4).

#define D 16
#define NWMAX 1024
#define NB 256      // sort chunks
#define BTS 1024    // sort-phase threads per block
#define SEG 4

// ---------------- fallback naive kernel (R1, 137us) ----------------
__global__ __launch_bounds__(256) void linear_gather_mv(
    const float* __restrict__ values, const float* __restrict__ weight,
    const int* __restrict__ input_idx, const int* __restrict__ weight_idx,
    float* __restrict__ out, int E)
{
    int tid = blockIdx.x * blockDim.x + threadIdx.x;
    int e = tid >> 2;
    int j = tid & 3;
    if (e >= E) return;
    int ii = input_idx[e];
    int wi = weight_idx[e];
    const float4* xp = (const float4*)(values + (long long)ii * D);
    float4 x0 = xp[0], x1 = xp[1], x2 = xp[2], x3 = xp[3];
    const float4* wp = (const float4*)(weight + (long long)wi * (D * D) + j * (4 * D));
    float4 acc;
    float* accp = (float*)&acc;
    #pragma unroll
    for (int r = 0; r < 4; ++r) {
        float4 w0 = wp[r * 4 + 0], w1 = wp[r * 4 + 1], w2 = wp[r * 4 + 2], w3 = wp[r * 4 + 3];
        accp[r] = w0.x * x0.x + w0.y * x0.y + w0.z * x0.z + w0.w * x0.w
                + w1.x * x1.x + w1.y * x1.y + w1.z * x1.z + w1.w * x1.w
                + w2.x * x2.x + w2.y * x2.y + w2.z * x2.z + w2.w * x2.w
                + w3.x * x3.x + w3.y * x3.y + w3.z * x3.z + w3.w * x3.w;
    }
    ((float4*)out)[(long long)e * 4 + j] = acc;
}

// ---------------- phase 1: per-block private histograms ----------------
__global__ __launch_bounds__(BTS) void hist_blocks(
    const int* __restrict__ widx, int E, int chunk,
    int* __restrict__ hist2d, int NW)
{
    __shared__ int lh[NWMAX];
    for (int i = threadIdx.x; i < NW; i += BTS) lh[i] = 0;
    __syncthreads();
    int s0 = blockIdx.x * chunk;
    int s1 = min(E, s0 + chunk);
    for (int e = s0 + threadIdx.x; e < s1; e += BTS)
        atomicAdd(&lh[widx[e]], 1);   // LDS atomic only
    __syncthreads();
    int* row = hist2d + (long long)blockIdx.x * NW;
    for (int i = threadIdx.x; i < NW; i += BTS) row[i] = lh[i];
}

// ------- phase 2a: per-bin exclusive scan across blocks (in place) -------
__global__ __launch_bounds__(NB) void scan_per_bin(
    int* __restrict__ hist2d, int* __restrict__ total, int NW)
{
    __shared__ int buf[2 * NB];
    int b = blockIdx.x;   // bin
    int t = threadIdx.x;  // sort-block index
    int v = hist2d[(long long)t * NW + b];
    buf[t] = v;
    __syncthreads();
    int pin = 0;
    for (int off = 1; off < NB; off <<= 1) {
        int x = buf[pin * NB + t];
        if (t >= off) x += buf[pin * NB + t - off];
        buf[(1 - pin) * NB + t] = x;
        pin = 1 - pin;
        __syncthreads();
    }
    int incl = buf[pin * NB + t];
    hist2d[(long long)t * NW + b] = incl - v;   // exclusive prefix for (bin, block)
    if (t == NB - 1) total[b] = incl;
}

// ---------------- phase 2b: scan over bins -> bucket offsets ----------------
__global__ __launch_bounds__(1024) void scan_bins(
    const int* __restrict__ total, int* __restrict__ offsets, int NW)
{
    __shared__ int buf[2 * NWMAX];
    int t = threadIdx.x;
    int v = (t < NW) ? total[t] : 0;
    buf[t] = v;
    __syncthreads();
    int pin = 0;
    for (int off = 1; off < NWMAX; off <<= 1) {
        int x = buf[pin * NWMAX + t];
        if (t >= off) x += buf[pin * NWMAX + t - off];
        buf[(1 - pin) * NWMAX + t] = x;
        pin = 1 - pin;
        __syncthreads();
    }
    int incl = buf[pin * NWMAX + t];
    if (t < NW) {
        offsets[t + 1] = incl;
        if (t == 0) offsets[0] = 0;
    }
}

// ---------------- phase 3: deterministic scatter, LDS cursors ----------------
__global__ __launch_bounds__(BTS) void scatter_det(
    const int* __restrict__ widx, const int* __restrict__ iidx, int E, int chunk,
    const int* __restrict__ hist2d, const int* __restrict__ offsets,
    int2* __restrict__ perm, int NW)
{
    __shared__ int cur[NWMAX];
    int p = blockIdx.x;
    const int* row = hist2d + (long long)p * NW;
    for (int i = threadIdx.x; i < NW; i += BTS)
        cur[i] = offsets[i] + row[i];
    __syncthreads();
    int s0 = p * chunk;
    int s1 = min(E, s0 + chunk);
    for (int e = s0 + threadIdx.x; e < s1; e += BTS) {
        int wi = widx[e];
        int pos = atomicAdd(&cur[wi], 1);   // LDS atomic
        perm[pos] = make_int2(e, iidx[e]);
    }
}

// 16-row dot: acc component r uses rows 4r..4r+3 slab selected by wp base
#define DOT16(ACC, X0, X1, X2, X3) do {                                        \
    ACC.x = w00.x*X0.x + w00.y*X0.y + w00.z*X0.z + w00.w*X0.w                  \
          + w01.x*X1.x + w01.y*X1.y + w01.z*X1.z + w01.w*X1.w                  \
          + w02.x*X2.x + w02.y*X2.y + w02.z*X2.z + w02.w*X2.w                  \
          + w03.x*X3.x + w03.y*X3.y + w03.z*X3.z + w03.w*X3.w;                 \
    ACC.y = w10.x*X0.x + w10.y*X0.y + w10.z*X0.z + w10.w*X0.w                  \
          + w11.x*X1.x + w11.y*X1.y + w11.z*X1.z + w11.w*X1.w                  \
          + w12.x*X2.x + w12.y*X2.y + w12.z*X2.z + w12.w*X2.w                  \
          + w13.x*X3.x + w13.y*X3.y + w13.z*X3.z + w13.w*X3.w;                 \
    ACC.z = w20.x*X0.x + w20.y*X0.y + w20.z*X0.z + w20.w*X0.w                  \
          + w21.x*X1.x + w21.y*X1.y + w21.z*X1.z + w21.w*X1.w                  \
          + w22.x*X2.x + w22.y*X2.y + w22.z*X2.z + w22.w*X2.w                  \
          + w23.x*X3.x + w23.y*X3.y + w23.z*X3.z + w23.w*X3.w;                 \
    ACC.w = w30.x*X0.x + w30.y*X0.y + w30.z*X0.z + w30.w*X0.w                  \
          + w31.x*X1.x + w31.y*X1.y + w31.z*X1.z + w31.w*X1.w                  \
          + w32.x*X2.x + w32.y*X2.y + w32.z*X2.z + w32.w*X2.w                  \
          + w33.x*X3.x + w33.y*X3.y + w33.z*X3.z + w33.w*X3.w;                 \
} while (0)

// ---- phase 4: per-bucket matvec, W pinned in 64 VGPRs, 2-way unrolled ----
// __launch_bounds__(256, 4): min 4 waves/EU -> 128-VGPR budget. W(64) +
// 2x X(32) + 2x acc(8) + addressing fits; compiler keeps W resident.
__global__ __launch_bounds__(256, 4) void bucket_mv(
    const float* __restrict__ values, const float* __restrict__ weight,
    const int* __restrict__ offsets, const int2* __restrict__ perm,
    float* __restrict__ out)
{
    int b = blockIdx.x;
    int lo = offsets[b], hi = offsets[b + 1];
    int cnt = hi - lo;
    if (cnt == 0) return;
    int per = (cnt + SEG - 1) / SEG;
    int s0 = lo + blockIdx.y * per;
    int s1 = min(hi, s0 + per);
    if (s0 >= s1) return;

    int j = threadIdx.x & 3;             // output row slab
    int g = threadIdx.x >> 2;            // connection group

    const float4* wp = (const float4*)(weight + (long long)b * (D * D) + j * (4 * D));
    float4 w00 = wp[0],  w01 = wp[1],  w02 = wp[2],  w03 = wp[3];
    float4 w10 = wp[4],  w11 = wp[5],  w12 = wp[6],  w13 = wp[7];
    float4 w20 = wp[8],  w21 = wp[9],  w22 = wp[10], w23 = wp[11];
    float4 w30 = wp[12], w31 = wp[13], w32 = wp[14], w33 = wp[15];

    for (int k = s0 + g; k < s1; k += 128) {
        int k1 = k + 64;
        bool h1 = (k1 < s1);
        int2 p0 = perm[k];
        int2 p1 = h1 ? perm[k1] : p0;

        // two independent gather chains in flight
        const float4* xa = (const float4*)(values + (long long)p0.y * D);
        const float4* xb = (const float4*)(values + (long long)p1.y * D);
        float4 a0 = xa[0], a1 = xa[1], a2 = xa[2], a3 = xa[3];
        float4 b0 = xb[0], b1 = xb[1], b2 = xb[2], b3 = xb[3];

        float4 acc0, acc1;
        DOT16(acc0, a0, a1, a2, a3);
        ((float4*)out)[(long long)p0.x * 4 + j] = acc0;
        if (h1) {
            DOT16(acc1, b0, b1, b2, b3);
            ((float4*)out)[(long long)p1.x * 4 + j] = acc1;
        }
    }
}

extern "C" void kernel_launch(void* const* d_in, const int* in_sizes, int n_in,
                              void* d_out, int out_size, void* d_ws, size_t ws_size,
                              hipStream_t stream) {
    const float* values     = (const float*)d_in[0];
    const float* weight     = (const float*)d_in[1];
    const int*   input_idx  = (const int*)d_in[2];
    const int*   weight_idx = (const int*)d_in[3];
    float*       out        = (float*)d_out;

    int E  = in_sizes[2];
    int NW = in_sizes[1] / (D * D);
    int chunk = (E + NB - 1) / NB;

    // workspace: hist2d[NB*NW] | total[NW] | offsets[NW+1] | pad | perm[2E]
    size_t n_hist = (size_t)NB * NW;
    size_t n_head = n_hist + NW + NW + 1;
    n_head = (n_head + 1) & ~(size_t)1;
    size_t need = (n_head + 2 * (size_t)E) * sizeof(int);

    if (NW > NWMAX || ws_size < need) {
        int total_thr = E * 4;
        int grid = (total_thr + 255) / 256;
        hipLaunchKernelGGL(linear_gather_mv, dim3(grid), dim3(256), 0, stream,
                           values, weight, input_idx, weight_idx, out, E);
        return;
    }

    int* hist2d  = (int*)d_ws;
    int* total   = hist2d + n_hist;
    int* offsets = total + NW;
    int2* perm   = (int2*)((int*)d_ws + n_head);

    hipLaunchKernelGGL(hist_blocks, dim3(NB), dim3(BTS), 0, stream,
                       weight_idx, E, chunk, hist2d, NW);
    hipLaunchKernelGGL(scan_per_bin, dim3(NW), dim3(NB), 0, stream,
                       hist2d, total, NW);
    hipLaunchKernelGGL(scan_bins, dim3(1), dim3(1024), 0, stream,
                       total, offsets, NW);
    hipLaunchKernelGGL(scatter_det, dim3(NB), dim3(BTS), 0, stream,
                       weight_idx, input_idx, E, chunk, hist2d, offsets, perm, NW);
    hipLaunchKernelGGL(bucket_mv, dim3(NW, SEG), dim3(256), 0, stream,
                       values, weight, offsets, perm, out);
}

// Round 6
// 163.207 us; speedup vs baseline: 1.5716x; 1.0188x over previous
//
#include <hip/hip_runtime.h>

// y[e, o] = sum_i weight[widx[e]][o][i] * values[iidx[e]][i]
// E = 1e6, N_W = 1024, D_IN = D_OUT = 16, fp32.
//
// R1: weight gather latency-bound -> 137 us kernel (211 total => ~70 us
//     fixed harness overhead in dur_us, confirmed by kernel timestamps).
// R2: global-atomic scatter serialized -> 203 us.
// R3/R5: sort works; bucket_mv VGPR_Count=48 even with launch_bounds(256,4)
//     -> compiler refuses to keep 64-reg W resident, re-fetches W per iter.
// R6: W in LDS (1KB/block, loaded once; no W global traffic at all),
//     4-way unroll over CONTIGUOUS sorted connections (4 independent
//     perm->x chains, coalesced perm loads), SEG=4.

#define D 16
#define NWMAX 1024
#define NB 256      // sort chunks
#define BTS 1024    // sort-phase threads per block
#define SEG 4

// ---------------- fallback naive kernel (R1, 137us) ----------------
__global__ __launch_bounds__(256) void linear_gather_mv(
    const float* __restrict__ values, const float* __restrict__ weight,
    const int* __restrict__ input_idx, const int* __restrict__ weight_idx,
    float* __restrict__ out, int E)
{
    int tid = blockIdx.x * blockDim.x + threadIdx.x;
    int e = tid >> 2;
    int j = tid & 3;
    if (e >= E) return;
    int ii = input_idx[e];
    int wi = weight_idx[e];
    const float4* xp = (const float4*)(values + (long long)ii * D);
    float4 x0 = xp[0], x1 = xp[1], x2 = xp[2], x3 = xp[3];
    const float4* wp = (const float4*)(weight + (long long)wi * (D * D) + j * (4 * D));
    float4 acc;
    float* accp = (float*)&acc;
    #pragma unroll
    for (int r = 0; r < 4; ++r) {
        float4 w0 = wp[r * 4 + 0], w1 = wp[r * 4 + 1], w2 = wp[r * 4 + 2], w3 = wp[r * 4 + 3];
        accp[r] = w0.x * x0.x + w0.y * x0.y + w0.z * x0.z + w0.w * x0.w
                + w1.x * x1.x + w1.y * x1.y + w1.z * x1.z + w1.w * x1.w
                + w2.x * x2.x + w2.y * x2.y + w2.z * x2.z + w2.w * x2.w
                + w3.x * x3.x + w3.y * x3.y + w3.z * x3.z + w3.w * x3.w;
    }
    ((float4*)out)[(long long)e * 4 + j] = acc;
}

// ---------------- phase 1: per-block private histograms ----------------
__global__ __launch_bounds__(BTS) void hist_blocks(
    const int* __restrict__ widx, int E, int chunk,
    int* __restrict__ hist2d, int NW)
{
    __shared__ int lh[NWMAX];
    for (int i = threadIdx.x; i < NW; i += BTS) lh[i] = 0;
    __syncthreads();
    int s0 = blockIdx.x * chunk;
    int s1 = min(E, s0 + chunk);
    for (int e = s0 + threadIdx.x; e < s1; e += BTS)
        atomicAdd(&lh[widx[e]], 1);
    __syncthreads();
    int* row = hist2d + (long long)blockIdx.x * NW;
    for (int i = threadIdx.x; i < NW; i += BTS) row[i] = lh[i];
}

// ------- phase 2a: per-bin exclusive scan across blocks (in place) -------
__global__ __launch_bounds__(NB) void scan_per_bin(
    int* __restrict__ hist2d, int* __restrict__ total, int NW)
{
    __shared__ int buf[2 * NB];
    int b = blockIdx.x;
    int t = threadIdx.x;
    int v = hist2d[(long long)t * NW + b];
    buf[t] = v;
    __syncthreads();
    int pin = 0;
    for (int off = 1; off < NB; off <<= 1) {
        int x = buf[pin * NB + t];
        if (t >= off) x += buf[pin * NB + t - off];
        buf[(1 - pin) * NB + t] = x;
        pin = 1 - pin;
        __syncthreads();
    }
    int incl = buf[pin * NB + t];
    hist2d[(long long)t * NW + b] = incl - v;
    if (t == NB - 1) total[b] = incl;
}

// ---------------- phase 2b: scan over bins -> bucket offsets ----------------
__global__ __launch_bounds__(1024) void scan_bins(
    const int* __restrict__ total, int* __restrict__ offsets, int NW)
{
    __shared__ int buf[2 * NWMAX];
    int t = threadIdx.x;
    int v = (t < NW) ? total[t] : 0;
    buf[t] = v;
    __syncthreads();
    int pin = 0;
    for (int off = 1; off < NWMAX; off <<= 1) {
        int x = buf[pin * NWMAX + t];
        if (t >= off) x += buf[pin * NWMAX + t - off];
        buf[(1 - pin) * NWMAX + t] = x;
        pin = 1 - pin;
        __syncthreads();
    }
    int incl = buf[pin * NWMAX + t];
    if (t < NW) {
        offsets[t + 1] = incl;
        if (t == 0) offsets[0] = 0;
    }
}

// ---------------- phase 3: deterministic scatter, LDS cursors ----------------
__global__ __launch_bounds__(BTS) void scatter_det(
    const int* __restrict__ widx, const int* __restrict__ iidx, int E, int chunk,
    const int* __restrict__ hist2d, const int* __restrict__ offsets,
    int2* __restrict__ perm, int NW)
{
    __shared__ int cur[NWMAX];
    int p = blockIdx.x;
    const int* row = hist2d + (long long)p * NW;
    for (int i = threadIdx.x; i < NW; i += BTS)
        cur[i] = offsets[i] + row[i];
    __syncthreads();
    int s0 = p * chunk;
    int s1 = min(E, s0 + chunk);
    for (int e = s0 + threadIdx.x; e < s1; e += BTS) {
        int wi = widx[e];
        int pos = atomicAdd(&cur[wi], 1);
        perm[pos] = make_int2(e, iidx[e]);
    }
}

// 16-row dot using W in float4 registers w00..w33
#define DOT16(ACC, X0, X1, X2, X3) do {                                        \
    ACC.x = w00.x*X0.x + w00.y*X0.y + w00.z*X0.z + w00.w*X0.w                  \
          + w01.x*X1.x + w01.y*X1.y + w01.z*X1.z + w01.w*X1.w                  \
          + w02.x*X2.x + w02.y*X2.y + w02.z*X2.z + w02.w*X2.w                  \
          + w03.x*X3.x + w03.y*X3.y + w03.z*X3.z + w03.w*X3.w;                 \
    ACC.y = w10.x*X0.x + w10.y*X0.y + w10.z*X0.z + w10.w*X0.w                  \
          + w11.x*X1.x + w11.y*X1.y + w11.z*X1.z + w11.w*X1.w                  \
          + w12.x*X2.x + w12.y*X2.y + w12.z*X2.z + w12.w*X2.w                  \
          + w13.x*X3.x + w13.y*X3.y + w13.z*X3.z + w13.w*X3.w;                 \
    ACC.z = w20.x*X0.x + w20.y*X0.y + w20.z*X0.z + w20.w*X0.w                  \
          + w21.x*X1.x + w21.y*X1.y + w21.z*X1.z + w21.w*X1.w                  \
          + w22.x*X2.x + w22.y*X2.y + w22.z*X2.z + w22.w*X2.w                  \
          + w23.x*X3.x + w23.y*X3.y + w23.z*X3.z + w23.w*X3.w;                 \
    ACC.w = w30.x*X0.x + w30.y*X0.y + w30.z*X0.z + w30.w*X0.w                  \
          + w31.x*X1.x + w31.y*X1.y + w31.z*X1.z + w31.w*X1.w                  \
          + w32.x*X2.x + w32.y*X2.y + w32.z*X2.z + w32.w*X2.w                  \
          + w33.x*X3.x + w33.y*X3.y + w33.z*X3.z + w33.w*X3.w;                 \
} while (0)

// ---- phase 4: per-bucket matvec. W staged in LDS (1KB), 4-way unrolled
// over contiguous sorted connections: 4 independent perm->x chains.
__global__ __launch_bounds__(256, 4) void bucket_mv(
    const float* __restrict__ values, const float* __restrict__ weight,
    const int* __restrict__ offsets, const int2* __restrict__ perm,
    float* __restrict__ out)
{
    __shared__ float Wl[D * D];
    int b = blockIdx.x;
    // stage W[b] into LDS: 256 threads, one float each, coalesced
    Wl[threadIdx.x] = weight[(long long)b * (D * D) + threadIdx.x];

    int lo = offsets[b], hi = offsets[b + 1];
    int cnt = hi - lo;
    __syncthreads();
    if (cnt == 0) return;
    int per = (cnt + SEG - 1) / SEG;
    int s0 = lo + blockIdx.y * per;
    int s1 = min(hi, s0 + per);
    if (s0 >= s1) return;

    int j = threadIdx.x & 3;             // output row slab
    int g = threadIdx.x >> 2;            // connection group (0..63)

    // W slab rows 4j..4j+3 from LDS (compiler may hoist; LDS re-read is cheap)
    const float4* wl = (const float4*)(Wl + j * (4 * D));
    float4 w00 = wl[0],  w01 = wl[1],  w02 = wl[2],  w03 = wl[3];
    float4 w10 = wl[4],  w11 = wl[5],  w12 = wl[6],  w13 = wl[7];
    float4 w20 = wl[8],  w21 = wl[9],  w22 = wl[10], w23 = wl[11];
    float4 w30 = wl[12], w31 = wl[13], w32 = wl[14], w33 = wl[15];

    // group g handles 4 CONTIGUOUS sorted connections per iteration
    for (int k0 = s0 + 4 * g; k0 < s1; k0 += 256) {
        int k1 = k0 + 1, k2 = k0 + 2, k3 = k0 + 3;
        bool h1 = k1 < s1, h2 = k2 < s1, h3 = k3 < s1;
        int2 p0 = perm[k0];
        int2 p1 = h1 ? perm[k1] : p0;
        int2 p2 = h2 ? perm[k2] : p0;
        int2 p3 = h3 ? perm[k3] : p0;

        // 4 independent gather chains
        const float4* xa = (const float4*)(values + (long long)p0.y * D);
        const float4* xb = (const float4*)(values + (long long)p1.y * D);
        const float4* xc = (const float4*)(values + (long long)p2.y * D);
        const float4* xd = (const float4*)(values + (long long)p3.y * D);
        float4 a0 = xa[0], a1 = xa[1], a2 = xa[2], a3 = xa[3];
        float4 b0 = xb[0], b1 = xb[1], b2 = xb[2], b3 = xb[3];
        float4 c0 = xc[0], c1 = xc[1], c2 = xc[2], c3 = xc[3];
        float4 d0 = xd[0], d1 = xd[1], d2 = xd[2], d3 = xd[3];

        float4 acc;
        DOT16(acc, a0, a1, a2, a3);
        ((float4*)out)[(long long)p0.x * 4 + j] = acc;
        if (h1) {
            DOT16(acc, b0, b1, b2, b3);
            ((float4*)out)[(long long)p1.x * 4 + j] = acc;
        }
        if (h2) {
            DOT16(acc, c0, c1, c2, c3);
            ((float4*)out)[(long long)p2.x * 4 + j] = acc;
        }
        if (h3) {
            DOT16(acc, d0, d1, d2, d3);
            ((float4*)out)[(long long)p3.x * 4 + j] = acc;
        }
    }
}

extern "C" void kernel_launch(void* const* d_in, const int* in_sizes, int n_in,
                              void* d_out, int out_size, void* d_ws, size_t ws_size,
                              hipStream_t stream) {
    const float* values     = (const float*)d_in[0];
    const float* weight     = (const float*)d_in[1];
    const int*   input_idx  = (const int*)d_in[2];
    const int*   weight_idx = (const int*)d_in[3];
    float*       out        = (float*)d_out;

    int E  = in_sizes[2];
    int NW = in_sizes[1] / (D * D);
    int chunk = (E + NB - 1) / NB;

    // workspace: hist2d[NB*NW] | total[NW] | offsets[NW+1] | pad | perm[2E]
    size_t n_hist = (size_t)NB * NW;
    size_t n_head = n_hist + NW + NW + 1;
    n_head = (n_head + 1) & ~(size_t)1;
    size_t need = (n_head + 2 * (size_t)E) * sizeof(int);

    if (NW > NWMAX || ws_size < need) {
        int total_thr = E * 4;
        int grid = (total_thr + 255) / 256;
        hipLaunchKernelGGL(linear_gather_mv, dim3(grid), dim3(256), 0, stream,
                           values, weight, input_idx, weight_idx, out, E);
        return;
    }

    int* hist2d  = (int*)d_ws;
    int* total   = hist2d + n_hist;
    int* offsets = total + NW;
    int2* perm   = (int2*)((int*)d_ws + n_head);

    hipLaunchKernelGGL(hist_blocks, dim3(NB), dim3(BTS), 0, stream,
                       weight_idx, E, chunk, hist2d, NW);
    hipLaunchKernelGGL(scan_per_bin, dim3(NW), dim3(NB), 0, stream,
                       hist2d, total, NW);
    hipLaunchKernelGGL(scan_bins, dim3(1), dim3(1024), 0, stream,
                       total, offsets, NW);
    hipLaunchKernelGGL(scatter_det, dim3(NB), dim3(BTS), 0, stream,
                       weight_idx, input_idx, E, chunk, hist2d, offsets, perm, NW);
    hipLaunchKernelGGL(bucket_mv, dim3(NW, SEG), dim3(256), 0, stream,
                       values, weight, offsets, perm, out);
}